// Round 2
// baseline (3639.817 us; speedup 1.0000x reference)
//
#include <hip/hip_runtime.h>
#include <math.h>

// Problem constants (from reference): B=64, T=2048, D=128, H=100, F=300
constexpr int H_ = 100;
constexpr int D_ = 128;
constexpr int F_ = 300;
constexpr int T_ = 2048;
constexpr int B_ = 64;
constexpr int G_ = 4 * H_;   // 400 gate outputs

static __device__ __forceinline__ float fast_rcp(float x) {
    return __builtin_amdgcn_rcpf(x);
}
static __device__ __forceinline__ float sigmoid_f(float g) {
    return fast_rcp(1.f + __expf(-g));
}
static __device__ __forceinline__ float tanh_f(float g) {
    float gg = fminf(fmaxf(g, -15.f), 15.f);
    float e = __expf(2.f * gg);
    return (e - 1.f) * fast_rcp(e + 1.f);
}

// ---------------------------------------------------------------------------
// Kernel A: xg[B*T, 400] = x[B*T,128] @ W_ih^T + (b_ih + b_hh)
// Block: 512 threads, 32 rows per block. Thread j<400 owns output column j,
// W_ih row j preloaded to registers, x rows staged in LDS (broadcast reads).
// ---------------------------------------------------------------------------
constexpr int AROWS = 32;

__global__ __launch_bounds__(512, 2) void xg_gemm(
    const float* __restrict__ x, const float* __restrict__ W_ih,
    const float* __restrict__ b_ih, const float* __restrict__ b_hh,
    float* __restrict__ xg)
{
    __shared__ float xs[AROWS * D_];   // [32][128] = 16 KB
    const int tid = threadIdx.x;
    const long rowbase = (long)blockIdx.x * AROWS;

    {   // coalesced float4 stage of the x tile
        const float4* gx = (const float4*)(x + rowbase * D_);
        float4* sx = (float4*)xs;
        for (int i = tid; i < AROWS * D_ / 4; i += 512) sx[i] = gx[i];
    }
    __syncthreads();

    if (tid < G_) {
        float w[D_];
        const float4* wp = (const float4*)(W_ih + tid * D_);
        #pragma unroll
        for (int k4 = 0; k4 < D_ / 4; ++k4) {
            float4 v = wp[k4];
            w[4*k4+0] = v.x; w[4*k4+1] = v.y; w[4*k4+2] = v.z; w[4*k4+3] = v.w;
        }
        const float bias = b_ih[tid] + b_hh[tid];

        #pragma unroll 1
        for (int g = 0; g < AROWS / 4; ++g) {
            float a0 = bias, a1 = bias, a2 = bias, a3 = bias;
            const float4* r0 = (const float4*)&xs[(4*g + 0) * D_];
            const float4* r1 = (const float4*)&xs[(4*g + 1) * D_];
            const float4* r2 = (const float4*)&xs[(4*g + 2) * D_];
            const float4* r3 = (const float4*)&xs[(4*g + 3) * D_];
            #pragma unroll 8
            for (int k4 = 0; k4 < D_ / 4; ++k4) {
                float4 v0 = r0[k4], v1 = r1[k4], v2 = r2[k4], v3 = r3[k4];
                a0 = fmaf(w[4*k4+0], v0.x, a0); a0 = fmaf(w[4*k4+1], v0.y, a0);
                a0 = fmaf(w[4*k4+2], v0.z, a0); a0 = fmaf(w[4*k4+3], v0.w, a0);
                a1 = fmaf(w[4*k4+0], v1.x, a1); a1 = fmaf(w[4*k4+1], v1.y, a1);
                a1 = fmaf(w[4*k4+2], v1.z, a1); a1 = fmaf(w[4*k4+3], v1.w, a1);
                a2 = fmaf(w[4*k4+0], v2.x, a2); a2 = fmaf(w[4*k4+1], v2.y, a2);
                a2 = fmaf(w[4*k4+2], v2.z, a2); a2 = fmaf(w[4*k4+3], v2.w, a2);
                a3 = fmaf(w[4*k4+0], v3.x, a3); a3 = fmaf(w[4*k4+1], v3.y, a3);
                a3 = fmaf(w[4*k4+2], v3.z, a3); a3 = fmaf(w[4*k4+3], v3.w, a3);
            }
            float* orow = xg + (rowbase + 4*g) * G_ + tid;
            orow[0 * G_] = a0; orow[1 * G_] = a1;
            orow[2 * G_] = a2; orow[3 * G_] = a3;
        }
    }
}

// ---------------------------------------------------------------------------
// Kernel B: LSTM recurrence. One block per batch element (64 blocks).
// Thread j<400 owns gate pre-activation j: g_j = xg[t][j] + W_hh[j,:]·h
// (W_hh row in 100 VGPRs, h broadcast from LDS). The same thread applies
// its gate's activation; threads 0..99 then update c (register) and h (LDS).
// xg is prefetched 2 steps ahead (HBM latency > step latency).
// ---------------------------------------------------------------------------
__global__ __launch_bounds__(512, 2) void lstm_rec(
    const float* __restrict__ xg,    // [B, T, 400]
    const float* __restrict__ W_hh,  // [400, 100]
    float* __restrict__ hout)        // [B, T, 100]
{
    __shared__ float h_lds[H_];
    __shared__ float a_lds[G_];
    const int j = threadIdx.x;
    const int b = blockIdx.x;
    const float* xgb = xg + (long)b * T_ * G_;
    float* hb = hout + (long)b * T_ * H_;

    float w[H_];
    if (j < G_) {
        const float4* wp = (const float4*)(W_hh + j * H_);
        #pragma unroll
        for (int k4 = 0; k4 < H_ / 4; ++k4) {
            float4 v = wp[k4];
            w[4*k4+0] = v.x; w[4*k4+1] = v.y; w[4*k4+2] = v.z; w[4*k4+3] = v.w;
        }
    }
    if (j < H_) h_lds[j] = 0.f;
    float c = 0.f;

    float xg_c = (j < G_) ? xgb[j] : 0.f;
    float xg_n = (j < G_) ? xgb[G_ + j] : 0.f;
    __syncthreads();

    #define LSTM_STEP(XGV, TIDX)                                             \
    {                                                                        \
        if (j < G_) {                                                        \
            float a0 = (XGV), a1 = 0.f, a2 = 0.f, a3 = 0.f;                  \
            _Pragma("unroll")                                                \
            for (int k4 = 0; k4 < H_ / 4; ++k4) {                            \
                float4 hv = *(const float4*)&h_lds[4 * k4];                  \
                a0 = fmaf(w[4*k4+0], hv.x, a0);                              \
                a1 = fmaf(w[4*k4+1], hv.y, a1);                              \
                a2 = fmaf(w[4*k4+2], hv.z, a2);                              \
                a3 = fmaf(w[4*k4+3], hv.w, a3);                              \
            }                                                                \
            float gv = (a0 + a1) + (a2 + a3);                                \
            float act;                                                       \
            if (j < 2 * H_ || j >= 3 * H_) act = sigmoid_f(gv);              \
            else                            act = tanh_f(gv);                \
            a_lds[j] = act;                                                  \
        }                                                                    \
        __syncthreads();                                                     \
        if (j < H_) {                                                        \
            float ig = a_lds[j], fg = a_lds[H_ + j];                         \
            float gg = a_lds[2 * H_ + j], og = a_lds[3 * H_ + j];            \
            c = fmaf(fg, c, ig * gg);                                        \
            float hv = og * tanh_f(c);                                       \
            h_lds[j] = hv;                                                   \
            hb[(long)(TIDX) * H_ + j] = hv;                                  \
        }                                                                    \
        __syncthreads();                                                     \
    }

    for (int t = 0; t < T_; t += 2) {
        float p0 = (j < G_ && t + 2 < T_) ? xgb[(long)(t + 2) * G_ + j] : 0.f;
        float p1 = (j < G_ && t + 3 < T_) ? xgb[(long)(t + 3) * G_ + j] : 0.f;
        LSTM_STEP(xg_c, t);
        LSTM_STEP(xg_n, t + 1);
        xg_c = p0; xg_n = p1;
    }
    #undef LSTM_STEP
}

// ---------------------------------------------------------------------------
// Kernel C: fused FFN. out = relu(relu(h) @ ff1^T + b1) @ ff2^T + b2
// Block: 512 threads, 32 rows. Stage 1: thread j<300 owns ff1 column j
// (weights in registers, h rows broadcast from LDS). Stage 2: all 512
// threads: col = tid&127, 8-row group = tid>>7, ff2 weights from L2.
// ---------------------------------------------------------------------------
constexpr int CROWS = 32;

__global__ __launch_bounds__(512, 2) void ffn(
    const float* __restrict__ hin,   // [B*T, 100]
    const float* __restrict__ ff1_w, const float* __restrict__ ff1_b,
    const float* __restrict__ ff2_w, const float* __restrict__ ff2_b,
    float* __restrict__ out)         // [B*T, 128]
{
    __shared__ float hs[CROWS * H_];   // 12.8 KB
    __shared__ float fs[CROWS * F_];   // 38.4 KB
    const int tid = threadIdx.x;
    const long rowbase = (long)blockIdx.x * CROWS;

    {   // stage h tile with relu applied
        const float4* gh = (const float4*)(hin + rowbase * H_);
        float4* sh = (float4*)hs;
        for (int i = tid; i < CROWS * H_ / 4; i += 512) {
            float4 v = gh[i];
            v.x = fmaxf(v.x, 0.f); v.y = fmaxf(v.y, 0.f);
            v.z = fmaxf(v.z, 0.f); v.w = fmaxf(v.w, 0.f);
            sh[i] = v;
        }
    }
    __syncthreads();

    if (tid < F_) {
        float w[H_];
        const float4* wp = (const float4*)(ff1_w + tid * H_);
        #pragma unroll
        for (int k4 = 0; k4 < H_ / 4; ++k4) {
            float4 v = wp[k4];
            w[4*k4+0] = v.x; w[4*k4+1] = v.y; w[4*k4+2] = v.z; w[4*k4+3] = v.w;
        }
        const float bias = ff1_b[tid];
        #pragma unroll 1
        for (int g = 0; g < CROWS / 4; ++g) {
            float a0 = bias, a1 = bias, a2 = bias, a3 = bias;
            const float4* r0 = (const float4*)&hs[(4*g + 0) * H_];
            const float4* r1 = (const float4*)&hs[(4*g + 1) * H_];
            const float4* r2 = (const float4*)&hs[(4*g + 2) * H_];
            const float4* r3 = (const float4*)&hs[(4*g + 3) * H_];
            #pragma unroll
            for (int k4 = 0; k4 < H_ / 4; ++k4) {
                float4 v0 = r0[k4], v1 = r1[k4], v2 = r2[k4], v3 = r3[k4];
                a0 = fmaf(w[4*k4+0], v0.x, a0); a0 = fmaf(w[4*k4+1], v0.y, a0);
                a0 = fmaf(w[4*k4+2], v0.z, a0); a0 = fmaf(w[4*k4+3], v0.w, a0);
                a1 = fmaf(w[4*k4+0], v1.x, a1); a1 = fmaf(w[4*k4+1], v1.y, a1);
                a1 = fmaf(w[4*k4+2], v1.z, a1); a1 = fmaf(w[4*k4+3], v1.w, a1);
                a2 = fmaf(w[4*k4+0], v2.x, a2); a2 = fmaf(w[4*k4+1], v2.y, a2);
                a2 = fmaf(w[4*k4+2], v2.z, a2); a2 = fmaf(w[4*k4+3], v2.w, a2);
                a3 = fmaf(w[4*k4+0], v3.x, a3); a3 = fmaf(w[4*k4+1], v3.y, a3);
                a3 = fmaf(w[4*k4+2], v3.z, a3); a3 = fmaf(w[4*k4+3], v3.w, a3);
            }
            fs[(4*g + 0) * F_ + tid] = fmaxf(a0, 0.f);
            fs[(4*g + 1) * F_ + tid] = fmaxf(a1, 0.f);
            fs[(4*g + 2) * F_ + tid] = fmaxf(a2, 0.f);
            fs[(4*g + 3) * F_ + tid] = fmaxf(a3, 0.f);
        }
    }
    __syncthreads();

    {   // stage 2: all 512 threads
        const int col = tid & (D_ - 1);
        const int rg  = tid >> 7;          // 0..3 -> rows rg*8 .. rg*8+7
        const float4* wp = (const float4*)(ff2_w + col * F_);
        const float bias = ff2_b[col];
        float acc[8];
        #pragma unroll
        for (int r = 0; r < 8; ++r) acc[r] = bias;

        #pragma unroll 5
        for (int k4 = 0; k4 < F_ / 4; ++k4) {
            float4 wv = wp[k4];
            #pragma unroll
            for (int r = 0; r < 8; ++r) {
                const float4 v = *(const float4*)&fs[(rg * 8 + r) * F_ + 4 * k4];
                acc[r] = fmaf(wv.x, v.x, acc[r]);
                acc[r] = fmaf(wv.y, v.y, acc[r]);
                acc[r] = fmaf(wv.z, v.z, acc[r]);
                acc[r] = fmaf(wv.w, v.w, acc[r]);
            }
        }
        #pragma unroll
        for (int r = 0; r < 8; ++r)
            out[(rowbase + rg * 8 + r) * D_ + col] = acc[r];
    }
}

// ---------------------------------------------------------------------------
extern "C" void kernel_launch(void* const* d_in, const int* in_sizes, int n_in,
                              void* d_out, int out_size, void* d_ws, size_t ws_size,
                              hipStream_t stream) {
    const float* x     = (const float*)d_in[0];
    // d_in[1] = y (unused by the reference output)
    const float* W_ih  = (const float*)d_in[2];
    const float* W_hh  = (const float*)d_in[3];
    const float* b_ih  = (const float*)d_in[4];
    const float* b_hh  = (const float*)d_in[5];
    const float* ff1_w = (const float*)d_in[6];
    const float* ff1_b = (const float*)d_in[7];
    const float* ff2_w = (const float*)d_in[8];
    const float* ff2_b = (const float*)d_in[9];
    float* out = (float*)d_out;

    float* xg   = (float*)d_ws;                       // [B*T, 400] = 210 MB
    float* hbuf = xg + (long)B_ * T_ * G_;            // [B*T, 100] =  52 MB

    xg_gemm<<<(B_ * T_) / AROWS, 512, 0, stream>>>(x, W_ih, b_ih, b_hh, xg);
    lstm_rec<<<B_, 512, 0, stream>>>(xg, W_hh, hbuf);
    ffn<<<(B_ * T_) / CROWS, 512, 0, stream>>>(hbuf, ff1_w, ff1_b, ff2_w, ff2_b, out);
}